// Round 1
// baseline (1203.973 us; speedup 1.0000x reference)
//
#include <hip/hip_runtime.h>

// AGNN / GatedGCN layer for MI355X (gfx950).
// v2: scatter-atomic aggregation replaced by counting-sort (by src) + segment-sum.
// ws layout (bytes), total ~297.7 MB:
//   [0)          wt: 7 weights, bf16, transposed [n][k], 7*16384 ushort = 229376
//   [229376)     hQ (N*D f32, 25.6MB), hR, hU, hV, xbuf  (5 x 25.6MB)
//   [+128MB)     ehat (E*D bf16, 163.84MB)
//   [+163.84MB)  stats slots: esum/esq/nsum/nsq (32x128 f32, 64KB) + sce/she/scn/shn (2KB)
//   [+67584)     sort: cnt (50176 i32), offs (50176 i32), sorted (E int2 = 5.12MB)

#define NN 50000
#define NE 640000
#define D 128

typedef unsigned int uint32;
typedef unsigned short u16;
typedef short bf16x8 __attribute__((ext_vector_type(8)));
typedef float floatx4 __attribute__((ext_vector_type(4)));

__device__ __forceinline__ u16 f2bf(float f) {
  uint32 u = __float_as_uint(f);
  u += 0x7fffu + ((u >> 16) & 1u);
  return (u16)(u >> 16);
}
__device__ __forceinline__ float bfu2f(uint32 lo16) { return __uint_as_float(lo16 << 16); }
__device__ __forceinline__ uint32 pack2(float a, float b) {
  return (uint32)f2bf(a) | ((uint32)f2bf(b) << 16);
}

// 64x128 @ 128x128 MFMA tile: Xs [64][136] bf16 row-major (m,k), Ws [128][136] bf16 (n,k).
__device__ __forceinline__ void mfma_tile64(const u16* __restrict__ Xs,
                                            const u16* __restrict__ Ws,
                                            floatx4 acc[8], int wave, int lane) {
  const int q = lane >> 4, l = lane & 15;
  const u16* ax = Xs + (wave * 16 + l) * 136 + q * 8;
  const u16* bx = Ws + l * 136 + q * 8;
#pragma unroll
  for (int kk = 0; kk < 4; ++kk) {
    bf16x8 a = *(const bf16x8*)(ax + kk * 32);
#pragma unroll
    for (int nt = 0; nt < 8; ++nt) {
      bf16x8 b = *(const bf16x8*)(bx + nt * 16 * 136 + kk * 32);
      acc[nt] = __builtin_amdgcn_mfma_f32_16x16x32_bf16(a, b, acc[nt], 0, 0, 0);
    }
  }
}

// K1: convert 7 weights [k][n] f32 -> transposed bf16 [n][k]
__global__ __launch_bounds__(256) void k_wconv(
    const float* __restrict__ Pw, const float* __restrict__ Qw, const float* __restrict__ Rw,
    const float* __restrict__ Uw, const float* __restrict__ Vw, const float* __restrict__ W1,
    const float* __restrict__ W2, u16* __restrict__ wt) {
  int b = blockIdx.x;
  const float* s = (b == 0) ? Pw : (b == 1) ? Qw : (b == 2) ? Rw : (b == 3) ? Uw
                 : (b == 4) ? Vw : (b == 5) ? W1 : W2;
  u16* dstp = wt + b * 16384;
  for (int idx = threadIdx.x; idx < 16384; idx += 256) {
    int k = idx >> 7, n = idx & 127;
    dstp[n * 128 + k] = f2bf(s[idx]);
  }
}

// K2: hQ/hR/hU/hV = h @ {Qw,Rw,Uw,Vw}
__global__ __launch_bounds__(256) void k_node_gemm(
    const float* __restrict__ h, const u16* __restrict__ wt, float* __restrict__ hQ,
    float* __restrict__ hR, float* __restrict__ hU, float* __restrict__ hV) {
  __shared__ u16 Xs[64 * 136];
  __shared__ u16 Ws[128 * 136];
  const int tid = threadIdx.x;
  const int wave = tid >> 6, lane = tid & 63;
  const int q = lane >> 4, l = lane & 15;
  const int row0 = blockIdx.x * 64;

#pragma unroll
  for (int it = 0; it < 8; ++it) {
    int idx = (it * 256 + tid) * 4;
    int r = idx >> 7, c = idx & 127;
    int g = row0 + r;
    float4 v = make_float4(0.f, 0.f, 0.f, 0.f);
    if (g < NN) v = *(const float4*)(h + (size_t)g * D + c);
    uint2 p;
    p.x = pack2(v.x, v.y);
    p.y = pack2(v.z, v.w);
    *(uint2*)(Xs + r * 136 + c) = p;
  }

  float* const outs[4] = {hQ, hR, hU, hV};
#pragma unroll
  for (int wi = 0; wi < 4; ++wi) {
#pragma unroll
    for (int it = 0; it < 8; ++it) {
      int idx = (it * 256 + tid) * 8;
      *(uint4*)(Ws + (idx >> 7) * 136 + (idx & 127)) =
          *(const uint4*)(wt + (wi + 1) * 16384 + idx);
    }
    __syncthreads();
    floatx4 acc[8] = {};
    mfma_tile64(Xs, Ws, acc, wave, lane);
    float* outp = outs[wi];
#pragma unroll
    for (int nt = 0; nt < 8; ++nt) {
#pragma unroll
      for (int r = 0; r < 4; ++r) {
        int m = wave * 16 + q * 4 + r;
        int g = row0 + m;
        if (g < NN) outp[(size_t)g * D + nt * 16 + l] = acc[nt][r];
      }
    }
    __syncthreads();
  }
}

// K_hist: histogram of src
__global__ __launch_bounds__(256) void k_hist(const int* __restrict__ src,
                                              int* __restrict__ cnt) {
  int i = blockIdx.x * 256 + threadIdx.x;
  if (i < NE) atomicAdd(&cnt[src[i]], 1);
}

// K_scan: exclusive prefix sum of cnt -> offs. Single block, 1024 threads x 49 elems.
__global__ __launch_bounds__(1024) void k_scan(const int* __restrict__ cnt,
                                               int* __restrict__ offs) {
  __shared__ int part[1024];
  const int t = threadIdx.x;
  const int base = t * 49;
  int s = 0;
  for (int j = 0; j < 49; ++j) {
    int i = base + j;
    if (i < NN) s += cnt[i];
  }
  part[t] = s;
  __syncthreads();
  for (int d = 1; d < 1024; d <<= 1) {
    int v = (t >= d) ? part[t - d] : 0;
    __syncthreads();
    part[t] += v;
    __syncthreads();
  }
  int run = (t == 0) ? 0 : part[t - 1];
  for (int j = 0; j < 49; ++j) {
    int i = base + j;
    if (i < NN) {
      offs[i] = run;
      run += cnt[i];
    }
  }
}

// K_scatter: sorted[pos] = (edge_id, dst). offs[s] is mutated to segment END.
__global__ __launch_bounds__(256) void k_scatter(const int* __restrict__ src,
                                                 const int* __restrict__ dst,
                                                 int* __restrict__ offs,
                                                 int2* __restrict__ sorted) {
  int i = blockIdx.x * 256 + threadIdx.x;
  if (i < NE) {
    int s = src[i];
    int p = atomicAdd(&offs[s], 1);
    sorted[p] = make_int2(i, dst[i]);
  }
}

// K3: ehat = e@P + hQ[src] + hR[dst]; store bf16; BN-e stats partials.
// (aggregation moved to k_agg — no global atomics here)
__global__ __launch_bounds__(256) void k_edge1(
    const float* __restrict__ e, const int* __restrict__ src, const int* __restrict__ dst,
    const u16* __restrict__ wt, const float* __restrict__ hQ, const float* __restrict__ hR,
    u16* __restrict__ ehat, float* __restrict__ esum, float* __restrict__ esq) {
  __shared__ u16 Xs[64 * 136];
  __shared__ u16 Ws[128 * 136];
  __shared__ int sSrc[64], sDst[64];
  __shared__ float sSum[128], sSq[128];
  const int tid = threadIdx.x;
  const int wave = tid >> 6, lane = tid & 63;
  const int q = lane >> 4, l = lane & 15;
  const int row0 = blockIdx.x * 64;

  if (tid < 128) { sSum[tid] = 0.f; sSq[tid] = 0.f; }
  if (tid < 64) { sSrc[tid] = src[row0 + tid]; sDst[tid] = dst[row0 + tid]; }
#pragma unroll
  for (int it = 0; it < 8; ++it) {
    int idx = (it * 256 + tid) * 4;
    int r = idx >> 7, c = idx & 127;
    float4 v = *(const float4*)(e + (size_t)(row0 + r) * D + c);
    uint2 p;
    p.x = pack2(v.x, v.y);
    p.y = pack2(v.z, v.w);
    *(uint2*)(Xs + r * 136 + c) = p;
  }
#pragma unroll
  for (int it = 0; it < 8; ++it) {
    int idx = (it * 256 + tid) * 8;
    *(uint4*)(Ws + (idx >> 7) * 136 + (idx & 127)) = *(const uint4*)(wt + idx);  // Pw
  }
  __syncthreads();

  floatx4 acc[8] = {};
  mfma_tile64(Xs, Ws, acc, wave, lane);

  float cs[8] = {}, cq[8] = {};
#pragma unroll
  for (int nt = 0; nt < 8; ++nt) {
    const int n = nt * 16 + l;
#pragma unroll
    for (int r = 0; r < 4; ++r) {
      const int m = wave * 16 + q * 4 + r;
      const int s = sSrc[m], dd = sDst[m];
      float v = acc[nt][r] + hQ[(size_t)s * D + n] + hR[(size_t)dd * D + n];
      ehat[(size_t)(row0 + m) * D + n] = f2bf(v);
      cs[nt] += v;
      cq[nt] += v * v;
    }
  }
#pragma unroll
  for (int nt = 0; nt < 8; ++nt) {
    cs[nt] += __shfl_xor(cs[nt], 16);
    cs[nt] += __shfl_xor(cs[nt], 32);
    cq[nt] += __shfl_xor(cq[nt], 16);
    cq[nt] += __shfl_xor(cq[nt], 32);
    if (q == 0) {
      atomicAdd(&sSum[nt * 16 + l], cs[nt]);
      atomicAdd(&sSq[nt * 16 + l], cq[nt]);
    }
  }
  __syncthreads();
  if (tid < 128) {
    atomicAdd(&esum[(blockIdx.x & 31) * D + tid], sSum[tid]);
    atomicAdd(&esq[(blockIdx.x & 31) * D + tid], sSq[tid]);
  }
}

// K_agg: segment-sum per node: x = hU + sum_{edges with src=n} sigmoid(ehat)*hV[dst].
// 32 lanes per node (float4/lane covers D=128), 8 nodes per 256-thread block.
// Also produces BN-n stats partials (k_node_stats eliminated).
__global__ __launch_bounds__(256) void k_agg(
    const u16* __restrict__ ehat, const float* __restrict__ hV, const float* __restrict__ hU,
    const int* __restrict__ cnt, const int* __restrict__ offs, const int2* __restrict__ sorted,
    float* __restrict__ xb, float* __restrict__ nsum, float* __restrict__ nsq) {
  __shared__ float sSum[128], sSq[128];
  const int tid = threadIdx.x;
  if (tid < 128) { sSum[tid] = 0.f; sSq[tid] = 0.f; }
  __syncthreads();
  const int lane = tid & 31;
  const int n = blockIdx.x * 8 + (tid >> 5);  // 6250*8 == NN exactly
  const int end = offs[n];                    // offs was advanced to END by k_scatter
  const int deg = cnt[n];
  const int p0 = end - deg;
  float4 acc = make_float4(0.f, 0.f, 0.f, 0.f);
  for (int k = 0; k < deg; ++k) {
    int2 ed = sorted[p0 + k];
    uint2 ev = *(const uint2*)(ehat + (size_t)ed.x * D + lane * 4);
    float4 v = *(const float4*)(hV + (size_t)ed.y * D + lane * 4);
    acc.x += v.x / (1.f + __expf(-bfu2f(ev.x & 0xffffu)));
    acc.y += v.y / (1.f + __expf(-bfu2f(ev.x >> 16)));
    acc.z += v.z / (1.f + __expf(-bfu2f(ev.y & 0xffffu)));
    acc.w += v.w / (1.f + __expf(-bfu2f(ev.y >> 16)));
  }
  float4 u = *(const float4*)(hU + (size_t)n * D + lane * 4);
  float4 x = make_float4(u.x + acc.x, u.y + acc.y, u.z + acc.z, u.w + acc.w);
  *(float4*)(xb + (size_t)n * D + lane * 4) = x;
  atomicAdd(&sSum[lane * 4 + 0], x.x);
  atomicAdd(&sSum[lane * 4 + 1], x.y);
  atomicAdd(&sSum[lane * 4 + 2], x.z);
  atomicAdd(&sSum[lane * 4 + 3], x.w);
  atomicAdd(&sSq[lane * 4 + 0], x.x * x.x);
  atomicAdd(&sSq[lane * 4 + 1], x.y * x.y);
  atomicAdd(&sSq[lane * 4 + 2], x.z * x.z);
  atomicAdd(&sSq[lane * 4 + 3], x.w * x.w);
  __syncthreads();
  if (tid < 128) {
    atomicAdd(&nsum[(blockIdx.x & 31) * D + tid], sSum[tid]);
    atomicAdd(&nsq[(blockIdx.x & 31) * D + tid], sSq[tid]);
  }
}

// K5: finalize both BNs into scale/shift
__global__ __launch_bounds__(128) void k_finalize(
    const float* __restrict__ esum, const float* __restrict__ esq,
    const float* __restrict__ nsum, const float* __restrict__ nsq,
    const float* __restrict__ ge, const float* __restrict__ be, const float* __restrict__ gn,
    const float* __restrict__ bnb, float* __restrict__ sce, float* __restrict__ she,
    float* __restrict__ scn, float* __restrict__ shn) {
  const int t = threadIdx.x;
  float s = 0.f, q = 0.f;
  for (int i = 0; i < 32; ++i) { s += esum[i * D + t]; q += esq[i * D + t]; }
  float mean = s / (float)NE;
  float var = q / (float)NE - mean * mean;
  float istd = rsqrtf(var + 1e-5f);
  sce[t] = istd * ge[t];
  she[t] = be[t] - mean * istd * ge[t];
  s = 0.f; q = 0.f;
  for (int i = 0; i < 32; ++i) { s += nsum[i * D + t]; q += nsq[i * D + t]; }
  mean = s / (float)NN;
  var = q / (float)NN - mean * mean;
  istd = rsqrtf(var + 1e-5f);
  scn[t] = istd * gn[t];
  shn[t] = bnb[t] - mean * istd * gn[t];
}

// K6: e_new = e + relu(BN(ehat)@W1 + b1)@W2 + b2
__global__ __launch_bounds__(256) void k_edge2(
    const u16* __restrict__ ehat, const float* __restrict__ e, const u16* __restrict__ wt,
    const float* __restrict__ sce, const float* __restrict__ she, const float* __restrict__ b1,
    const float* __restrict__ b2, float* __restrict__ oute) {
  __shared__ u16 Ts[64 * 136];
  __shared__ u16 Ws[128 * 136];
  __shared__ float sSc[128], sSh[128], sB1[128], sB2[128];
  const int tid = threadIdx.x;
  const int wave = tid >> 6, lane = tid & 63;
  const int q = lane >> 4, l = lane & 15;
  const int row0 = blockIdx.x * 64;

  if (tid < 128) { sSc[tid] = sce[tid]; sSh[tid] = she[tid]; sB1[tid] = b1[tid]; sB2[tid] = b2[tid]; }
  __syncthreads();

#pragma unroll
  for (int it = 0; it < 4; ++it) {
    int idx = (it * 256 + tid) * 8;
    int r = idx >> 7, c = idx & 127;
    uint4 u = *(const uint4*)(ehat + (size_t)(row0 + r) * D + c);
    float f0 = bfu2f(u.x & 0xffffu) * sSc[c + 0] + sSh[c + 0];
    float f1 = bfu2f(u.x >> 16) * sSc[c + 1] + sSh[c + 1];
    float f2 = bfu2f(u.y & 0xffffu) * sSc[c + 2] + sSh[c + 2];
    float f3 = bfu2f(u.y >> 16) * sSc[c + 3] + sSh[c + 3];
    float f4 = bfu2f(u.z & 0xffffu) * sSc[c + 4] + sSh[c + 4];
    float f5 = bfu2f(u.z >> 16) * sSc[c + 5] + sSh[c + 5];
    float f6 = bfu2f(u.w & 0xffffu) * sSc[c + 6] + sSh[c + 6];
    float f7 = bfu2f(u.w >> 16) * sSc[c + 7] + sSh[c + 7];
    uint4 o;
    o.x = pack2(f0, f1); o.y = pack2(f2, f3); o.z = pack2(f4, f5); o.w = pack2(f6, f7);
    *(uint4*)(Ts + r * 136 + c) = o;
  }
#pragma unroll
  for (int it = 0; it < 8; ++it) {
    int idx = (it * 256 + tid) * 8;
    *(uint4*)(Ws + (idx >> 7) * 136 + (idx & 127)) = *(const uint4*)(wt + 5 * 16384 + idx);  // W1
  }
  __syncthreads();

  floatx4 acc[8] = {};
  mfma_tile64(Ts, Ws, acc, wave, lane);
  __syncthreads();  // all reads of Ts/Ws done before overwrite

#pragma unroll
  for (int nt = 0; nt < 8; ++nt) {
    int n = nt * 16 + l;
#pragma unroll
    for (int r = 0; r < 4; ++r) {
      int m = wave * 16 + q * 4 + r;
      float v = acc[nt][r] + sB1[n];
      Ts[m * 136 + n] = f2bf(fmaxf(v, 0.f));
    }
  }
#pragma unroll
  for (int it = 0; it < 8; ++it) {
    int idx = (it * 256 + tid) * 8;
    *(uint4*)(Ws + (idx >> 7) * 136 + (idx & 127)) = *(const uint4*)(wt + 6 * 16384 + idx);  // W2
  }
  __syncthreads();

  floatx4 acc2[8] = {};
  mfma_tile64(Ts, Ws, acc2, wave, lane);

#pragma unroll
  for (int nt = 0; nt < 8; ++nt) {
    int n = nt * 16 + l;
#pragma unroll
    for (int r = 0; r < 4; ++r) {
      int m = wave * 16 + q * 4 + r;
      size_t gi = (size_t)(row0 + m) * D + n;
      oute[gi] = e[gi] + acc2[nt][r] + sB2[n];
    }
  }
}

// K7: h_new = h + alpha * (x*scale + shift), x precomputed by k_agg
__global__ __launch_bounds__(256) void k_node_out(
    const float* __restrict__ h, const float* __restrict__ xb,
    const float* __restrict__ scn, const float* __restrict__ shn,
    const float* __restrict__ alphap, float* __restrict__ outh) {
  size_t idx = ((size_t)blockIdx.x * 256 + threadIdx.x) * 4;  // 6250*256*4 == NN*D
  int c = (int)(idx & 127);
  float al = alphap[0];
  float4 x = *(const float4*)(xb + idx);
  float4 hh = *(const float4*)(h + idx);
  float4 o;
  o.x = hh.x + al * (x.x * scn[c + 0] + shn[c + 0]);
  o.y = hh.y + al * (x.y * scn[c + 1] + shn[c + 1]);
  o.z = hh.z + al * (x.z * scn[c + 2] + shn[c + 2]);
  o.w = hh.w + al * (x.w * scn[c + 3] + shn[c + 3]);
  *(float4*)(outh + idx) = o;
}

extern "C" void kernel_launch(void* const* d_in, const int* in_sizes, int n_in, void* d_out,
                              int out_size, void* d_ws, size_t ws_size, hipStream_t stream) {
  const float* h = (const float*)d_in[0];
  const float* e = (const float*)d_in[1];
  const int* ei = (const int*)d_in[2];
  const float* Pw = (const float*)d_in[3];
  const float* Qw = (const float*)d_in[4];
  const float* Rw = (const float*)d_in[5];
  const float* Uw = (const float*)d_in[6];
  const float* Vw = (const float*)d_in[7];
  const float* W1 = (const float*)d_in[8];
  const float* b1 = (const float*)d_in[9];
  const float* W2 = (const float*)d_in[10];
  const float* b2 = (const float*)d_in[11];
  const float* ge = (const float*)d_in[12];
  const float* be = (const float*)d_in[13];
  const float* gn = (const float*)d_in[14];
  const float* bnb = (const float*)d_in[15];
  const float* al = (const float*)d_in[16];

  const int* srcp = ei;
  const int* dstp = ei + NE;

  char* ws = (char*)d_ws;
  u16* wt = (u16*)(ws);
  float* hQ = (float*)(ws + 229376ull);
  float* hR = (float*)(ws + 229376ull + 1ull * 25600000ull);
  float* hU = (float*)(ws + 229376ull + 2ull * 25600000ull);
  float* hV = (float*)(ws + 229376ull + 3ull * 25600000ull);
  float* xb = (float*)(ws + 229376ull + 4ull * 25600000ull);
  u16* ehat = (u16*)(ws + 229376ull + 5ull * 25600000ull);
  char* statb = ws + 229376ull + 5ull * 25600000ull + 163840000ull;
  float* esum = (float*)(statb);
  float* esq = (float*)(statb + 16384);
  float* nsum = (float*)(statb + 32768);
  float* nsq = (float*)(statb + 49152);
  float* sce = (float*)(statb + 65536);
  float* she = (float*)(statb + 65536 + 512);
  float* scn = (float*)(statb + 65536 + 1024);
  float* shn = (float*)(statb + 65536 + 1536);
  char* sortb = statb + 67584;
  int* cnt = (int*)(sortb);
  int* offs = (int*)(sortb + 200704);
  int2* sorted = (int2*)(sortb + 401408);

  float* outh = (float*)d_out;
  float* oute = outh + (size_t)NN * D;

  hipMemsetAsync(cnt, 0, 200704, stream);
  hipMemsetAsync(statb, 0, 65536, stream);

  k_wconv<<<7, 256, 0, stream>>>(Pw, Qw, Rw, Uw, Vw, W1, W2, wt);
  k_hist<<<2500, 256, 0, stream>>>(srcp, cnt);
  k_scan<<<1, 1024, 0, stream>>>(cnt, offs);
  k_scatter<<<2500, 256, 0, stream>>>(srcp, dstp, offs, sorted);
  k_node_gemm<<<782, 256, 0, stream>>>(h, wt, hQ, hR, hU, hV);
  k_edge1<<<10000, 256, 0, stream>>>(e, srcp, dstp, wt, hQ, hR, ehat, esum, esq);
  k_agg<<<6250, 256, 0, stream>>>(ehat, hV, hU, cnt, offs, sorted, xb, nsum, nsq);
  k_finalize<<<1, 128, 0, stream>>>(esum, esq, nsum, nsq, ge, be, gn, bnb, sce, she, scn, shn);
  k_edge2<<<10000, 256, 0, stream>>>(ehat, e, wt, sce, she, b1, b2, oute);
  k_node_out<<<6250, 256, 0, stream>>>(h, xb, scn, shn, al, outh);
}

// Round 2
// 1136.955 us; speedup vs baseline: 1.0589x; 1.0589x over previous
//
#include <hip/hip_runtime.h>

// AGNN / GatedGCN layer for MI355X (gfx950).
// v3: k_agg 4x unrolled (latency fix); GEMM kernels stage B in two 64-row halves
//     so LDS/block drops 53.8KB -> ~36KB => 4 blocks/CU (2x occupancy).
// ws layout (bytes):
//   [0)          wt: 7 weights, bf16, transposed [n][k], 7*16384 ushort = 229376
//   [229376)     hQ (N*D f32, 25.6MB), hR, hU, hV, xbuf  (5 x 25.6MB)
//   [+128MB)     ehat (E*D bf16, 163.84MB)
//   [+163.84MB)  stats: esum/esq/nsum/nsq (64KB) + sce/she/scn/shn (2KB)
//   [+67584)     sort: cnt (50176 i32), offs (50176 i32), sorted (E int2 = 5.12MB)

#define NN 50000
#define NE 640000
#define D 128

typedef unsigned int uint32;
typedef unsigned short u16;
typedef short bf16x8 __attribute__((ext_vector_type(8)));
typedef float floatx4 __attribute__((ext_vector_type(4)));

__device__ __forceinline__ u16 f2bf(float f) {
  uint32 u = __float_as_uint(f);
  u += 0x7fffu + ((u >> 16) & 1u);
  return (u16)(u >> 16);
}
__device__ __forceinline__ float bfu2f(uint32 lo16) { return __uint_as_float(lo16 << 16); }
__device__ __forceinline__ uint32 pack2(float a, float b) {
  return (uint32)f2bf(a) | ((uint32)f2bf(b) << 16);
}
__device__ __forceinline__ float fsigmoid(float x) {
  return __builtin_amdgcn_rcpf(1.f + __expf(-x));
}

// Half-tile MFMA: Xs [64][136] bf16 (m,k); Ws [64][136] bf16 holding B rows n0..n0+63.
// Fills acc[0..3] covering cols [16*nt_local .. ) within the half.
__device__ __forceinline__ void mfma_half(const u16* __restrict__ Xs,
                                          const u16* __restrict__ Ws,
                                          floatx4* __restrict__ acc, int wave, int lane) {
  const int q = lane >> 4, l = lane & 15;
  const u16* ax = Xs + (wave * 16 + l) * 136 + q * 8;
  const u16* bx = Ws + l * 136 + q * 8;
#pragma unroll
  for (int kk = 0; kk < 4; ++kk) {
    bf16x8 a = *(const bf16x8*)(ax + kk * 32);
#pragma unroll
    for (int nt = 0; nt < 4; ++nt) {
      bf16x8 b = *(const bf16x8*)(bx + nt * 16 * 136 + kk * 32);
      acc[nt] = __builtin_amdgcn_mfma_f32_16x16x32_bf16(a, b, acc[nt], 0, 0, 0);
    }
  }
}

// Stage one 64-row half of a transposed-bf16 weight into Ws (8192 u16).
__device__ __forceinline__ void stage_whalf(u16* __restrict__ Ws, const u16* __restrict__ wsrc,
                                            int tid) {
#pragma unroll
  for (int it = 0; it < 4; ++it) {
    int idx = (it * 256 + tid) * 8;
    *(uint4*)(Ws + (idx >> 7) * 136 + (idx & 127)) = *(const uint4*)(wsrc + idx);
  }
}

// K1: convert 7 weights [k][n] f32 -> transposed bf16 [n][k]
__global__ __launch_bounds__(256) void k_wconv(
    const float* __restrict__ Pw, const float* __restrict__ Qw, const float* __restrict__ Rw,
    const float* __restrict__ Uw, const float* __restrict__ Vw, const float* __restrict__ W1,
    const float* __restrict__ W2, u16* __restrict__ wt) {
  int b = blockIdx.x;
  const float* s = (b == 0) ? Pw : (b == 1) ? Qw : (b == 2) ? Rw : (b == 3) ? Uw
                 : (b == 4) ? Vw : (b == 5) ? W1 : W2;
  u16* dstp = wt + b * 16384;
  for (int idx = threadIdx.x; idx < 16384; idx += 256) {
    int k = idx >> 7, n = idx & 127;
    dstp[n * 128 + k] = f2bf(s[idx]);
  }
}

// K2: hQ/hR/hU/hV = h @ {Qw,Rw,Uw,Vw}
__global__ __launch_bounds__(256, 4) void k_node_gemm(
    const float* __restrict__ h, const u16* __restrict__ wt, float* __restrict__ hQ,
    float* __restrict__ hR, float* __restrict__ hU, float* __restrict__ hV) {
  __shared__ u16 Xs[64 * 136];
  __shared__ u16 Ws[64 * 136];
  const int tid = threadIdx.x;
  const int wave = tid >> 6, lane = tid & 63;
  const int q = lane >> 4, l = lane & 15;
  const int row0 = blockIdx.x * 64;

#pragma unroll
  for (int it = 0; it < 8; ++it) {
    int idx = (it * 256 + tid) * 4;
    int r = idx >> 7, c = idx & 127;
    int g = row0 + r;
    float4 v = make_float4(0.f, 0.f, 0.f, 0.f);
    if (g < NN) v = *(const float4*)(h + (size_t)g * D + c);
    uint2 p;
    p.x = pack2(v.x, v.y);
    p.y = pack2(v.z, v.w);
    *(uint2*)(Xs + r * 136 + c) = p;
  }

  float* const outs[4] = {hQ, hR, hU, hV};
#pragma unroll
  for (int wi = 0; wi < 4; ++wi) {
    __syncthreads();  // prior reads of Ws done
    stage_whalf(Ws, wt + (wi + 1) * 16384, tid);
    __syncthreads();
    floatx4 acc[8] = {};
    mfma_half(Xs, Ws, acc, wave, lane);
    __syncthreads();
    stage_whalf(Ws, wt + (wi + 1) * 16384 + 8192, tid);
    __syncthreads();
    mfma_half(Xs, Ws, acc + 4, wave, lane);
    float* outp = outs[wi];
#pragma unroll
    for (int nt = 0; nt < 8; ++nt) {
#pragma unroll
      for (int r = 0; r < 4; ++r) {
        int m = wave * 16 + q * 4 + r;
        int g = row0 + m;
        if (g < NN) outp[(size_t)g * D + nt * 16 + l] = acc[nt][r];
      }
    }
  }
}

// K_hist: histogram of src
__global__ __launch_bounds__(256) void k_hist(const int* __restrict__ src,
                                              int* __restrict__ cnt) {
  int i = blockIdx.x * 256 + threadIdx.x;
  if (i < NE) atomicAdd(&cnt[src[i]], 1);
}

// K_scan: exclusive prefix sum of cnt -> offs. Single block, 1024 threads x 49 elems.
__global__ __launch_bounds__(1024) void k_scan(const int* __restrict__ cnt,
                                               int* __restrict__ offs) {
  __shared__ int part[1024];
  const int t = threadIdx.x;
  const int base = t * 49;
  int s = 0;
#pragma unroll 7
  for (int j = 0; j < 49; ++j) {
    int i = base + j;
    if (i < NN) s += cnt[i];
  }
  part[t] = s;
  __syncthreads();
  for (int d = 1; d < 1024; d <<= 1) {
    int v = (t >= d) ? part[t - d] : 0;
    __syncthreads();
    part[t] += v;
    __syncthreads();
  }
  int run = (t == 0) ? 0 : part[t - 1];
  for (int j = 0; j < 49; ++j) {
    int i = base + j;
    if (i < NN) {
      offs[i] = run;
      run += cnt[i];
    }
  }
}

// K_scatter: sorted[pos] = (edge_id, dst). offs[s] is mutated to segment END.
__global__ __launch_bounds__(256) void k_scatter(const int* __restrict__ src,
                                                 const int* __restrict__ dst,
                                                 int* __restrict__ offs,
                                                 int2* __restrict__ sorted) {
  int i = blockIdx.x * 256 + threadIdx.x;
  if (i < NE) {
    int s = src[i];
    int p = atomicAdd(&offs[s], 1);
    sorted[p] = make_int2(i, dst[i]);
  }
}

// K3: ehat = e@P + hQ[src] + hR[dst]; store bf16; BN-e stats partials.
__global__ __launch_bounds__(256, 4) void k_edge1(
    const float* __restrict__ e, const int* __restrict__ src, const int* __restrict__ dst,
    const u16* __restrict__ wt, const float* __restrict__ hQ, const float* __restrict__ hR,
    u16* __restrict__ ehat, float* __restrict__ esum, float* __restrict__ esq) {
  __shared__ u16 Xs[64 * 136];
  __shared__ u16 Ws[64 * 136];
  __shared__ int sSrc[64], sDst[64];
  __shared__ float sSum[128], sSq[128];
  const int tid = threadIdx.x;
  const int wave = tid >> 6, lane = tid & 63;
  const int q = lane >> 4, l = lane & 15;
  const int row0 = blockIdx.x * 64;

  if (tid < 128) { sSum[tid] = 0.f; sSq[tid] = 0.f; }
  if (tid < 64) { sSrc[tid] = src[row0 + tid]; sDst[tid] = dst[row0 + tid]; }
#pragma unroll
  for (int it = 0; it < 8; ++it) {
    int idx = (it * 256 + tid) * 4;
    int r = idx >> 7, c = idx & 127;
    float4 v = *(const float4*)(e + (size_t)(row0 + r) * D + c);
    uint2 p;
    p.x = pack2(v.x, v.y);
    p.y = pack2(v.z, v.w);
    *(uint2*)(Xs + r * 136 + c) = p;
  }
  stage_whalf(Ws, wt, tid);  // Pw rows 0..63
  __syncthreads();

  floatx4 acc[8] = {};
  mfma_half(Xs, Ws, acc, wave, lane);
  __syncthreads();
  stage_whalf(Ws, wt + 8192, tid);  // Pw rows 64..127
  __syncthreads();
  mfma_half(Xs, Ws, acc + 4, wave, lane);

  float cs[8] = {}, cq[8] = {};
#pragma unroll
  for (int nt = 0; nt < 8; ++nt) {
    const int n = nt * 16 + l;
#pragma unroll
    for (int r = 0; r < 4; ++r) {
      const int m = wave * 16 + q * 4 + r;
      const int s = sSrc[m], dd = sDst[m];
      float v = acc[nt][r] + hQ[(size_t)s * D + n] + hR[(size_t)dd * D + n];
      ehat[(size_t)(row0 + m) * D + n] = f2bf(v);
      cs[nt] += v;
      cq[nt] += v * v;
    }
  }
#pragma unroll
  for (int nt = 0; nt < 8; ++nt) {
    cs[nt] += __shfl_xor(cs[nt], 16);
    cs[nt] += __shfl_xor(cs[nt], 32);
    cq[nt] += __shfl_xor(cq[nt], 16);
    cq[nt] += __shfl_xor(cq[nt], 32);
    if (q == 0) {
      atomicAdd(&sSum[nt * 16 + l], cs[nt]);
      atomicAdd(&sSq[nt * 16 + l], cq[nt]);
    }
  }
  __syncthreads();
  if (tid < 128) {
    atomicAdd(&esum[(blockIdx.x & 31) * D + tid], sSum[tid]);
    atomicAdd(&esq[(blockIdx.x & 31) * D + tid], sSq[tid]);
  }
}

// K_agg: x = hU + sum_{edges with src=n} sigmoid(ehat)*hV[dst], 4x unrolled.
// 32 lanes per node (float4/lane covers D=128), 8 nodes per 256-thread block.
// Also produces BN-n stats partials.
__global__ __launch_bounds__(256) void k_agg(
    const u16* __restrict__ ehat, const float* __restrict__ hV, const float* __restrict__ hU,
    const int* __restrict__ cnt, const int* __restrict__ offs, const int2* __restrict__ sorted,
    float* __restrict__ xb, float* __restrict__ nsum, float* __restrict__ nsq) {
  __shared__ float sSum[128], sSq[128];
  const int tid = threadIdx.x;
  if (tid < 128) { sSum[tid] = 0.f; sSq[tid] = 0.f; }
  __syncthreads();
  const int lane = tid & 31;
  const int n = blockIdx.x * 8 + (tid >> 5);  // 6250*8 == NN exactly
  const int end = offs[n];                    // offs advanced to END by k_scatter
  const int deg = cnt[n];
  const int p0 = end - deg;
  const int c4 = lane * 4;
  float4 acc = make_float4(0.f, 0.f, 0.f, 0.f);
  int k = 0;
  for (; k + 4 <= deg; k += 4) {
    int2 ed0 = sorted[p0 + k + 0];
    int2 ed1 = sorted[p0 + k + 1];
    int2 ed2 = sorted[p0 + k + 2];
    int2 ed3 = sorted[p0 + k + 3];
    uint2 ev0 = *(const uint2*)(ehat + (size_t)ed0.x * D + c4);
    uint2 ev1 = *(const uint2*)(ehat + (size_t)ed1.x * D + c4);
    uint2 ev2 = *(const uint2*)(ehat + (size_t)ed2.x * D + c4);
    uint2 ev3 = *(const uint2*)(ehat + (size_t)ed3.x * D + c4);
    float4 v0 = *(const float4*)(hV + (size_t)ed0.y * D + c4);
    float4 v1 = *(const float4*)(hV + (size_t)ed1.y * D + c4);
    float4 v2 = *(const float4*)(hV + (size_t)ed2.y * D + c4);
    float4 v3 = *(const float4*)(hV + (size_t)ed3.y * D + c4);
    acc.x += v0.x * fsigmoid(bfu2f(ev0.x & 0xffffu));
    acc.y += v0.y * fsigmoid(bfu2f(ev0.x >> 16));
    acc.z += v0.z * fsigmoid(bfu2f(ev0.y & 0xffffu));
    acc.w += v0.w * fsigmoid(bfu2f(ev0.y >> 16));
    acc.x += v1.x * fsigmoid(bfu2f(ev1.x & 0xffffu));
    acc.y += v1.y * fsigmoid(bfu2f(ev1.x >> 16));
    acc.z += v1.z * fsigmoid(bfu2f(ev1.y & 0xffffu));
    acc.w += v1.w * fsigmoid(bfu2f(ev1.y >> 16));
    acc.x += v2.x * fsigmoid(bfu2f(ev2.x & 0xffffu));
    acc.y += v2.y * fsigmoid(bfu2f(ev2.x >> 16));
    acc.z += v2.z * fsigmoid(bfu2f(ev2.y & 0xffffu));
    acc.w += v2.w * fsigmoid(bfu2f(ev2.y >> 16));
    acc.x += v3.x * fsigmoid(bfu2f(ev3.x & 0xffffu));
    acc.y += v3.y * fsigmoid(bfu2f(ev3.x >> 16));
    acc.z += v3.z * fsigmoid(bfu2f(ev3.y & 0xffffu));
    acc.w += v3.w * fsigmoid(bfu2f(ev3.y >> 16));
  }
  for (; k < deg; ++k) {
    int2 ed = sorted[p0 + k];
    uint2 ev = *(const uint2*)(ehat + (size_t)ed.x * D + c4);
    float4 v = *(const float4*)(hV + (size_t)ed.y * D + c4);
    acc.x += v.x * fsigmoid(bfu2f(ev.x & 0xffffu));
    acc.y += v.y * fsigmoid(bfu2f(ev.x >> 16));
    acc.z += v.z * fsigmoid(bfu2f(ev.y & 0xffffu));
    acc.w += v.w * fsigmoid(bfu2f(ev.y >> 16));
  }
  float4 u = *(const float4*)(hU + (size_t)n * D + c4);
  float4 x = make_float4(u.x + acc.x, u.y + acc.y, u.z + acc.z, u.w + acc.w);
  *(float4*)(xb + (size_t)n * D + c4) = x;
  atomicAdd(&sSum[c4 + 0], x.x);
  atomicAdd(&sSum[c4 + 1], x.y);
  atomicAdd(&sSum[c4 + 2], x.z);
  atomicAdd(&sSum[c4 + 3], x.w);
  atomicAdd(&sSq[c4 + 0], x.x * x.x);
  atomicAdd(&sSq[c4 + 1], x.y * x.y);
  atomicAdd(&sSq[c4 + 2], x.z * x.z);
  atomicAdd(&sSq[c4 + 3], x.w * x.w);
  __syncthreads();
  if (tid < 128) {
    atomicAdd(&nsum[(blockIdx.x & 31) * D + tid], sSum[tid]);
    atomicAdd(&nsq[(blockIdx.x & 31) * D + tid], sSq[tid]);
  }
}

// K5: finalize both BNs into scale/shift
__global__ __launch_bounds__(128) void k_finalize(
    const float* __restrict__ esum, const float* __restrict__ esq,
    const float* __restrict__ nsum, const float* __restrict__ nsq,
    const float* __restrict__ ge, const float* __restrict__ be, const float* __restrict__ gn,
    const float* __restrict__ bnb, float* __restrict__ sce, float* __restrict__ she,
    float* __restrict__ scn, float* __restrict__ shn) {
  const int t = threadIdx.x;
  float s = 0.f, q = 0.f;
  for (int i = 0; i < 32; ++i) { s += esum[i * D + t]; q += esq[i * D + t]; }
  float mean = s / (float)NE;
  float var = q / (float)NE - mean * mean;
  float istd = rsqrtf(var + 1e-5f);
  sce[t] = istd * ge[t];
  she[t] = be[t] - mean * istd * ge[t];
  s = 0.f; q = 0.f;
  for (int i = 0; i < 32; ++i) { s += nsum[i * D + t]; q += nsq[i * D + t]; }
  mean = s / (float)NN;
  var = q / (float)NN - mean * mean;
  istd = rsqrtf(var + 1e-5f);
  scn[t] = istd * gn[t];
  shn[t] = bnb[t] - mean * istd * gn[t];
}

// K6: e_new = e + relu(BN(ehat)@W1 + b1)@W2 + b2
__global__ __launch_bounds__(256, 4) void k_edge2(
    const u16* __restrict__ ehat, const float* __restrict__ e, const u16* __restrict__ wt,
    const float* __restrict__ sce, const float* __restrict__ she, const float* __restrict__ b1,
    const float* __restrict__ b2, float* __restrict__ oute) {
  __shared__ u16 Ts[64 * 136];
  __shared__ u16 Ws[64 * 136];
  __shared__ float sSc[128], sSh[128], sB1[128], sB2[128];
  const int tid = threadIdx.x;
  const int wave = tid >> 6, lane = tid & 63;
  const int q = lane >> 4, l = lane & 15;
  const int row0 = blockIdx.x * 64;

  if (tid < 128) { sSc[tid] = sce[tid]; sSh[tid] = she[tid]; sB1[tid] = b1[tid]; sB2[tid] = b2[tid]; }
  __syncthreads();

#pragma unroll
  for (int it = 0; it < 4; ++it) {
    int idx = (it * 256 + tid) * 8;
    int r = idx >> 7, c = idx & 127;
    uint4 u = *(const uint4*)(ehat + (size_t)(row0 + r) * D + c);
    float f0 = bfu2f(u.x & 0xffffu) * sSc[c + 0] + sSh[c + 0];
    float f1 = bfu2f(u.x >> 16) * sSc[c + 1] + sSh[c + 1];
    float f2 = bfu2f(u.y & 0xffffu) * sSc[c + 2] + sSh[c + 2];
    float f3 = bfu2f(u.y >> 16) * sSc[c + 3] + sSh[c + 3];
    float f4 = bfu2f(u.z & 0xffffu) * sSc[c + 4] + sSh[c + 4];
    float f5 = bfu2f(u.z >> 16) * sSc[c + 5] + sSh[c + 5];
    float f6 = bfu2f(u.w & 0xffffu) * sSc[c + 6] + sSh[c + 6];
    float f7 = bfu2f(u.w >> 16) * sSc[c + 7] + sSh[c + 7];
    uint4 o;
    o.x = pack2(f0, f1); o.y = pack2(f2, f3); o.z = pack2(f4, f5); o.w = pack2(f6, f7);
    *(uint4*)(Ts + r * 136 + c) = o;
  }
  stage_whalf(Ws, wt + 5 * 16384, tid);  // W1 rows 0..63
  __syncthreads();

  floatx4 acc[8] = {};
  mfma_half(Ts, Ws, acc, wave, lane);
  __syncthreads();
  stage_whalf(Ws, wt + 5 * 16384 + 8192, tid);  // W1 rows 64..127
  __syncthreads();
  mfma_half(Ts, Ws, acc + 4, wave, lane);
  __syncthreads();  // all reads of Ts done before overwrite

#pragma unroll
  for (int nt = 0; nt < 8; ++nt) {
    int n = nt * 16 + l;
#pragma unroll
    for (int r = 0; r < 4; ++r) {
      int m = wave * 16 + q * 4 + r;
      float v = acc[nt][r] + sB1[n];
      Ts[m * 136 + n] = f2bf(fmaxf(v, 0.f));
    }
  }
  stage_whalf(Ws, wt + 6 * 16384, tid);  // W2 rows 0..63
  __syncthreads();

  floatx4 acc2[8] = {};
  mfma_half(Ts, Ws, acc2, wave, lane);
  __syncthreads();
  stage_whalf(Ws, wt + 6 * 16384 + 8192, tid);  // W2 rows 64..127
  __syncthreads();
  mfma_half(Ts, Ws, acc2 + 4, wave, lane);

#pragma unroll
  for (int nt = 0; nt < 8; ++nt) {
    int n = nt * 16 + l;
#pragma unroll
    for (int r = 0; r < 4; ++r) {
      int m = wave * 16 + q * 4 + r;
      size_t gi = (size_t)(row0 + m) * D + n;
      oute[gi] = e[gi] + acc2[nt][r] + sB2[n];
    }
  }
}

// K7: h_new = h + alpha * (x*scale + shift), x precomputed by k_agg
__global__ __launch_bounds__(256) void k_node_out(
    const float* __restrict__ h, const float* __restrict__ xb,
    const float* __restrict__ scn, const float* __restrict__ shn,
    const float* __restrict__ alphap, float* __restrict__ outh) {
  size_t idx = ((size_t)blockIdx.x * 256 + threadIdx.x) * 4;  // 6250*256*4 == NN*D
  int c = (int)(idx & 127);
  float al = alphap[0];
  float4 x = *(const float4*)(xb + idx);
  float4 hh = *(const float4*)(h + idx);
  float4 o;
  o.x = hh.x + al * (x.x * scn[c + 0] + shn[c + 0]);
  o.y = hh.y + al * (x.y * scn[c + 1] + shn[c + 1]);
  o.z = hh.z + al * (x.z * scn[c + 2] + shn[c + 2]);
  o.w = hh.w + al * (x.w * scn[c + 3] + shn[c + 3]);
  *(float4*)(outh + idx) = o;
}

extern "C" void kernel_launch(void* const* d_in, const int* in_sizes, int n_in, void* d_out,
                              int out_size, void* d_ws, size_t ws_size, hipStream_t stream) {
  const float* h = (const float*)d_in[0];
  const float* e = (const float*)d_in[1];
  const int* ei = (const int*)d_in[2];
  const float* Pw = (const float*)d_in[3];
  const float* Qw = (const float*)d_in[4];
  const float* Rw = (const float*)d_in[5];
  const float* Uw = (const float*)d_in[6];
  const float* Vw = (const float*)d_in[7];
  const float* W1 = (const float*)d_in[8];
  const float* b1 = (const float*)d_in[9];
  const float* W2 = (const float*)d_in[10];
  const float* b2 = (const float*)d_in[11];
  const float* ge = (const float*)d_in[12];
  const float* be = (const float*)d_in[13];
  const float* gn = (const float*)d_in[14];
  const float* bnb = (const float*)d_in[15];
  const float* al = (const float*)d_in[16];

  const int* srcp = ei;
  const int* dstp = ei + NE;

  char* ws = (char*)d_ws;
  u16* wt = (u16*)(ws);
  float* hQ = (float*)(ws + 229376ull);
  float* hR = (float*)(ws + 229376ull + 1ull * 25600000ull);
  float* hU = (float*)(ws + 229376ull + 2ull * 25600000ull);
  float* hV = (float*)(ws + 229376ull + 3ull * 25600000ull);
  float* xb = (float*)(ws + 229376ull + 4ull * 25600000ull);
  u16* ehat = (u16*)(ws + 229376ull + 5ull * 25600000ull);
  char* statb = ws + 229376ull + 5ull * 25600000ull + 163840000ull;
  float* esum = (float*)(statb);
  float* esq = (float*)(statb + 16384);
  float* nsum = (float*)(statb + 32768);
  float* nsq = (float*)(statb + 49152);
  float* sce = (float*)(statb + 65536);
  float* she = (float*)(statb + 65536 + 512);
  float* scn = (float*)(statb + 65536 + 1024);
  float* shn = (float*)(statb + 65536 + 1536);
  char* sortb = statb + 67584;
  int* cnt = (int*)(sortb);
  int* offs = (int*)(sortb + 200704);
  int2* sorted = (int2*)(sortb + 401408);

  float* outh = (float*)d_out;
  float* oute = outh + (size_t)NN * D;

  // one contiguous memset covers stats (65536) + scale/shift (2048, overwritten
  // anyway) + cnt (200704)
  hipMemsetAsync(statb, 0, 67584 + 200704, stream);

  k_wconv<<<7, 256, 0, stream>>>(Pw, Qw, Rw, Uw, Vw, W1, W2, wt);
  k_hist<<<2500, 256, 0, stream>>>(srcp, cnt);
  k_scan<<<1, 1024, 0, stream>>>(cnt, offs);
  k_scatter<<<2500, 256, 0, stream>>>(srcp, dstp, offs, sorted);
  k_node_gemm<<<782, 256, 0, stream>>>(h, wt, hQ, hR, hU, hV);
  k_edge1<<<10000, 256, 0, stream>>>(e, srcp, dstp, wt, hQ, hR, ehat, esum, esq);
  k_agg<<<6250, 256, 0, stream>>>(ehat, hV, hU, cnt, offs, sorted, xb, nsum, nsq);
  k_finalize<<<1, 128, 0, stream>>>(esum, esq, nsum, nsq, ge, be, gn, bnb, sce, she, scn, shn);
  k_edge2<<<10000, 256, 0, stream>>>(ehat, e, wt, sce, she, b1, b2, oute);
  k_node_out<<<6250, 256, 0, stream>>>(h, xb, scn, shn, al, outh);
}